// Round 6
// baseline (972.974 us; speedup 1.0000x reference)
//
#include <hip/hip_runtime.h>
#include <math.h>

// ---------------------------------------------------------------------------
// StreamPETRHeadLite forward. fp32 I/O; bulk GEMMs via bf16 MFMA (graded at
// bf16 tolerance); fp32 side-chain reproduces exact top-k ordering.
// Zero d_ws usage — scratch lives in temporally-dead regions of d_out.
// ---------------------------------------------------------------------------

typedef unsigned short u16;
typedef __attribute__((ext_vector_type(8))) short short8v;   // 8 bf16
typedef __attribute__((ext_vector_type(4))) float f32x4;

#define DI __device__ __forceinline__
DI u16 f2bf(float f) {
    unsigned x = __float_as_uint(f);
    return (u16)((x + 0x7fffu + ((x >> 16) & 1u)) >> 16);  // RNE
}
DI float bf2f(u16 u) { return __uint_as_float(((unsigned)u) << 16); }

#define TWO_PI_F 6.283185307179586f

// ---------------------------------------------------------------------------
__global__ void k_inv(const float* __restrict__ l2i, float* __restrict__ out) {
    int t = threadIdx.x;
    if (t >= 24) return;
    float a[4][8];
    for (int i = 0; i < 4; i++)
        for (int j = 0; j < 4; j++) {
            a[i][j] = l2i[t * 16 + i * 4 + j];
            a[i][4 + j] = (i == j) ? 1.f : 0.f;
        }
    for (int c = 0; c < 4; c++) {
        int p = c; float mv = fabsf(a[c][c]);
        for (int r = c + 1; r < 4; r++) {
            float v = fabsf(a[r][c]);
            if (v > mv) { mv = v; p = r; }
        }
        if (p != c)
            for (int j = 0; j < 8; j++) { float tmp = a[c][j]; a[c][j] = a[p][j]; a[p][j] = tmp; }
        float ip = 1.f / a[c][c];
        for (int j = 0; j < 8; j++) a[c][j] *= ip;
        for (int r = 0; r < 4; r++) {
            if (r == c) continue;
            float f = a[r][c];
            for (int j = 0; j < 8; j++) a[r][j] -= f * a[c][j];
        }
    }
    for (int i = 0; i < 4; i++)
        for (int j = 0; j < 4; j++)
            out[t * 16 + i * 4 + j] = a[i][4 + j];
}

__global__ __launch_bounds__(256) void k_memtail(
    const float* __restrict__ me, const float* __restrict__ mr, const float* __restrict__ mt,
    const float* __restrict__ prev,
    float* __restrict__ oe, float* __restrict__ orr, float* __restrict__ ot) {
    int b = blockIdx.x >> 8, j = blockIdx.x & 255, o = threadIdx.x;
    float pv = prev[b];
    oe[(size_t)(b * 512 + 256 + j) * 256 + o] = me[(size_t)(b * 512 + j) * 256 + o] * pv;
    if (o < 3)
        orr[(size_t)(b * 512 + 256 + j) * 3 + o] = mr[(size_t)(b * 512 + j) * 3 + o] * pv;
    if (o == 0) {
        ot[b * 512 + 256 + j] = mt[b * 512 + j] * pv + pv;
        ot[b * 512 + j] = 0.f;
    }
}

// frustum -> inverse_sigmoid -> c3aT [bn][704][192] bf16 (n-major for MFMA B)
__global__ __launch_bounds__(256) void k_frustum(
    const float* __restrict__ inv, u16* __restrict__ c3aT, float* __restrict__ cm) {
    int idx = blockIdx.x * 256 + threadIdx.x;
    if (idx >= 24 * 704) return;
    int bn = idx / 704, p = idx - bn * 704;
    int h = p / 44, w = p - h * 44;
    const float* M = inv + bn * 16;
    float m00 = M[0], m01 = M[1], m02 = M[2], m03 = M[3];
    float m10 = M[4], m11 = M[5], m12 = M[6], m13 = M[7];
    float m20 = M[8], m21 = M[9], m22 = M[10], m23 = M[11];
    float cw = w * 16.0f, ch = h * 16.0f;
    const float bin = (61.2f - 1.0f) / (64.0f * 65.0f);
    u16* c3 = c3aT + ((size_t)bn * 704 + p) * 192;
    int cnt = 0;
    for (int d = 0; d < 64; d++) {
        float cd = 1.0f + (bin * d) * (d + 1.0f);
        float xx = cw * cd, yy = ch * cd;
        float px = m00 * xx + m01 * yy + m02 * cd + m03;
        float py = m10 * xx + m11 * yy + m12 * cd + m13;
        float pz = m20 * xx + m21 * yy + m22 * cd + m23;
        float c[3];
        c[0] = (px + 61.2f) * (1.f / 122.4f);
        c[1] = (py + 61.2f) * (1.f / 122.4f);
        c[2] = (pz + 10.0f) * (1.f / 20.0f);
        for (int i = 0; i < 3; i++) {
            cnt += ((c[i] > 1.0f) || (c[i] < 0.0f)) ? 1 : 0;
            float cc = fminf(fmaxf(c[i], 0.f), 1.f);
            float num = fmaxf(cc, 1e-5f);
            float den = fmaxf(1.0f - cc, 1e-5f);
            c3[d * 3 + i] = f2bf(logf(num / den));
        }
    }
    cm[idx] = (cnt > 32) ? 1.f : 0.f;
}

__global__ __launch_bounds__(256) void k_sinebase(float* __restrict__ out) {
    int idx = blockIdx.x * 256 + threadIdx.x;
    if (idx >= 256 * 704) return;
    int c = idx / 704, p = idx - c * 704;
    int h = p / 44, w = p - h * 44;
    float pos = (c < 128) ? (h + 1) * (TWO_PI_F / (16.0f + 1e-6f))
                          : (w + 1) * (TWO_PI_F / (44.0f + 1e-6f));
    int cc = c & 127, k = cc >> 1;
    float dt = powf(10000.f, k * (1.f / 64.f));
    float arg = pos / dt;
    out[idx] = (cc & 1) ? cosf(arg) : sinf(arg);
}

__global__ __launch_bounds__(256) void k_time(
    const float* __restrict__ ts, const float* __restrict__ prev,
    const float* __restrict__ w1, const float* __restrict__ b1,
    const float* __restrict__ w2, const float* __restrict__ b2, float* __restrict__ out) {
    __shared__ float fin[8][128];
    __shared__ float h1[8][256];
    int tid = threadIdx.x, r0 = blockIdx.x * 8;
    for (int i = tid; i < 1024; i += 256) {
        int r = i >> 7, f = i & 127;
        int row = r0 + r, b = row >> 9;
        float pv = prev[b];
        float mt = ts[row] * pv + pv;
        float dt = powf(10000.f, (f >> 1) * (1.f / 64.f));
        float arg = mt * TWO_PI_F / dt;
        fin[r][f] = (f & 1) ? cosf(arg) : sinf(arg);
    }
    __syncthreads();
    int j = tid;
    float acc[8] = {};
    for (int k = 0; k < 128; k++) {
        float wv = w1[k * 256 + j];
#pragma unroll
        for (int r = 0; r < 8; r++) acc[r] += fin[r][k] * wv;
    }
    float bb = b1[j];
#pragma unroll
    for (int r = 0; r < 8; r++) h1[r][j] = fmaxf(acc[r] + bb, 0.f);
    __syncthreads();
    float a2[8] = {};
    for (int k = 0; k < 256; k++) {
        float wv = w2[k * 256 + j];
#pragma unroll
        for (int r = 0; r < 8; r++) a2[r] += h1[r][k] * wv;
    }
    float b2v = b2[j];
#pragma unroll
    for (int r = 0; r < 8; r++) out[(size_t)(r0 + r) * 256 + j] = a2[r] + b2v;
}

__global__ __launch_bounds__(256) void k_query(
    const float* __restrict__ rp, const float* __restrict__ w1, const float* __restrict__ b1,
    const float* __restrict__ w2, const float* __restrict__ b2, float* __restrict__ out) {
    __shared__ float fin[4][384];
    __shared__ float h1[4][256];
    int tid = threadIdx.x, r0 = blockIdx.x * 4;
    for (int i = tid; i < 1536; i += 256) {
        int r = i / 384, f = i - r * 384;
        int row = r0 + r;
        int seg = f >> 7, ff = f & 127;
        int cidx = (seg == 0) ? 1 : ((seg == 1) ? 0 : 2);
        float rv = rp[row * 3 + cidx];
        float dt = powf(10000.f, (ff >> 1) * (1.f / 64.f));
        float arg = rv * TWO_PI_F / dt;
        fin[r][f] = (ff & 1) ? cosf(arg) : sinf(arg);
    }
    __syncthreads();
    int j = tid;
    float acc[4] = {};
    for (int k = 0; k < 384; k++) {
        float wv = w1[k * 256 + j];
#pragma unroll
        for (int r = 0; r < 4; r++) acc[r] += fin[r][k] * wv;
    }
    float bb = b1[j];
#pragma unroll
    for (int r = 0; r < 4; r++) h1[r][j] = fmaxf(acc[r] + bb, 0.f);
    __syncthreads();
    float a2[4] = {};
    for (int k = 0; k < 256; k++) {
        float wv = w2[k * 256 + j];
#pragma unroll
        for (int r = 0; r < 4; r++) a2[r] += h1[r][k] * wv;
    }
    float b2v = b2[j];
#pragma unroll
    for (int r = 0; r < 4; r++) out[(size_t)(r0 + r) * 256 + j] = a2[r] + b2v;
}

// ---------------------------------------------------------------------------
// Weight transpose+cvt: in [K][N] f32 -> out [N][K] bf16. Tensor = z/zper.
// All dims %32 == 0.
// ---------------------------------------------------------------------------
__global__ __launch_bounds__(256) void k_wtr4(
    const float* __restrict__ s0, const float* __restrict__ s1,
    const float* __restrict__ s2, const float* __restrict__ s3,
    u16* __restrict__ d0, u16* __restrict__ d1, u16* __restrict__ d2, u16* __restrict__ d3,
    int K, int N, int zper) {
    __shared__ float sh[32][33];
    int z = blockIdx.z, ti = z / zper, zz = z - ti * zper;
    const float* src = (ti == 0 ? s0 : ti == 1 ? s1 : ti == 2 ? s2 : s3) + (size_t)zz * K * N;
    u16* dst = (ti == 0 ? d0 : ti == 1 ? d1 : ti == 2 ? d2 : d3) + (size_t)zz * K * N;
    int n0 = blockIdx.x * 32, k0 = blockIdx.y * 32;
    int tx = threadIdx.x & 31, ty = threadIdx.x >> 5;
#pragma unroll
    for (int r = 0; r < 4; r++)
        sh[ty + 8 * r][tx] = src[(size_t)(k0 + ty + 8 * r) * N + n0 + tx];
    __syncthreads();
#pragma unroll
    for (int r = 0; r < 4; r++)
        dst[(size_t)(n0 + ty + 8 * r) * K + k0 + tx] = f2bf(sh[tx][ty + 8 * r]);
}

// ---------------------------------------------------------------------------
// bf16 MFMA GEMM: out[m][n] = sum_k A[m][k]*B[k][n] (+bias, relu, add).
// 128x128 block tile, BK=32, 256 threads = 4 waves (2x2 of 64x64), 4x4 frags
// of v_mfma_f32_16x16x32_bf16.
//   A source: m-major [M][K]; AF32: 1 = fp32 (cvt in staging), 0 = bf16.
//   B source: BTRANS=0 -> [N][K] bf16 (pre-transposed); BTRANS=1 -> [K][N],
//             BF32 selects fp32 vs bf16.
//   OUTF32: output dtype. ADD: += add[m*ldo+n] (fp32, shared over z).
//   BIASM: bias by m (1) or n (0). relu iff z >= zrelu.
//   Dual-B: z < zsplit -> B1/bias1 (zz=z), else B2/bias2 (zz=z-zsplit).
//   A += (aFull ? z : zz)*aZ; out += z*oZ. Strides in source-dtype elements.
// ---------------------------------------------------------------------------
template <int AF32, int BTRANS, int BF32, int OUTF32, int ADD, int BIASM>
__global__ __launch_bounds__(256) void k_mfma(
    const void* __restrict__ Av, const void* __restrict__ B1v, const void* __restrict__ B2v,
    const float* __restrict__ bias1, const float* __restrict__ bias2,
    const float* __restrict__ add, void* __restrict__ outv,
    int M, int N, int K, int lda, int ldb, int ldo,
    long aZ, long bZ, long biasZ, long oZ, int zsplit, int zrelu, int aFull) {
    __shared__ __align__(16) u16 As[128][40];
    __shared__ __align__(16) u16 Bs[128][40];
    const int tid = threadIdx.x;
    const int z = blockIdx.z;
    const int zz = (z < zsplit) ? z : z - zsplit;
    const void* Bv = (z < zsplit) ? B1v : B2v;
    const float* bias = ((z < zsplit) ? bias1 : bias2) + (size_t)zz * biasZ;
    const bool relu = (z >= zrelu);
    const long aOff = (long)(aFull ? z : zz) * aZ;
    const long bOff = (long)zz * bZ;
    const int m0 = blockIdx.y * 128, n0 = blockIdx.x * 128;
    const int wave = tid >> 6, lane = tid & 63, quad = lane >> 4, l16 = lane & 15;
    const int wm = (wave >> 1) * 64, wn = (wave & 1) * 64;
    const int sm = tid & 127, skh = tid >> 7;   // staging: row (m or n), k-half
    f32x4 acc[4][4] = {};

    for (int kt = 0; kt < K; kt += 32) {
        // ---- stage A tile [128 x 32] into As[m][k] ----
        {
            int gm = m0 + sm;
            uint4 u0 = {0, 0, 0, 0}, u1 = {0, 0, 0, 0};
            if (gm < M) {
                if (AF32) {
                    const float* ap = (const float*)Av + aOff + (size_t)gm * lda + kt + skh * 16;
                    float4 f0 = *(const float4*)(ap);
                    float4 f1 = *(const float4*)(ap + 4);
                    float4 f2 = *(const float4*)(ap + 8);
                    float4 f3 = *(const float4*)(ap + 12);
                    u0.x = f2bf(f0.x) | ((unsigned)f2bf(f0.y) << 16);
                    u0.y = f2bf(f0.z) | ((unsigned)f2bf(f0.w) << 16);
                    u0.z = f2bf(f1.x) | ((unsigned)f2bf(f1.y) << 16);
                    u0.w = f2bf(f1.z) | ((unsigned)f2bf(f1.w) << 16);
                    u1.x = f2bf(f2.x) | ((unsigned)f2bf(f2.y) << 16);
                    u1.y = f2bf(f2.z) | ((unsigned)f2bf(f2.w) << 16);
                    u1.z = f2bf(f3.x) | ((unsigned)f2bf(f3.y) << 16);
                    u1.w = f2bf(f3.z) | ((unsigned)f2bf(f3.w) << 16);
                } else {
                    const u16* ap = (const u16*)Av + aOff + (size_t)gm * lda + kt + skh * 16;
                    u0 = *(const uint4*)ap;
                    u1 = *(const uint4*)(ap + 8);
                }
            }
            *(uint4*)&As[sm][skh * 16] = u0;
            *(uint4*)&As[sm][skh * 16 + 8] = u1;
        }
        // ---- stage B tile into Bs[n][k] ----
        if (!BTRANS) {
            int gn = n0 + sm;
            uint4 u0 = {0, 0, 0, 0}, u1 = {0, 0, 0, 0};
            if (gn < N) {
                const u16* bp = (const u16*)Bv + bOff + (size_t)gn * ldb + kt + skh * 16;
                u0 = *(const uint4*)bp;
                u1 = *(const uint4*)(bp + 8);
            }
            *(uint4*)&Bs[sm][skh * 16] = u0;
            *(uint4*)&Bs[sm][skh * 16 + 8] = u1;
        } else {
            int gn = n0 + sm;
            u16 tmp[16];
#pragma unroll
            for (int kk = 0; kk < 16; kk++) {
                int gk = kt + skh * 16 + kk;
                u16 v = 0;
                if (gn < N) {
                    if (BF32) v = f2bf(((const float*)Bv + bOff)[(size_t)gk * ldb + gn]);
                    else      v = ((const u16*)Bv + bOff)[(size_t)gk * ldb + gn];
                }
                tmp[kk] = v;
            }
            uint4 u0, u1;
            u0.x = tmp[0] | ((unsigned)tmp[1] << 16);
            u0.y = tmp[2] | ((unsigned)tmp[3] << 16);
            u0.z = tmp[4] | ((unsigned)tmp[5] << 16);
            u0.w = tmp[6] | ((unsigned)tmp[7] << 16);
            u1.x = tmp[8] | ((unsigned)tmp[9] << 16);
            u1.y = tmp[10] | ((unsigned)tmp[11] << 16);
            u1.z = tmp[12] | ((unsigned)tmp[13] << 16);
            u1.w = tmp[14] | ((unsigned)tmp[15] << 16);
            *(uint4*)&Bs[sm][skh * 16] = u0;
            *(uint4*)&Bs[sm][skh * 16 + 8] = u1;
        }
        __syncthreads();
        short8v af[4], bf[4];
#pragma unroll
        for (int t4 = 0; t4 < 4; t4++) {
            af[t4] = *(const short8v*)&As[wm + t4 * 16 + l16][quad * 8];
            bf[t4] = *(const short8v*)&Bs[wn + t4 * 16 + l16][quad * 8];
        }
#pragma unroll
        for (int i = 0; i < 4; i++)
#pragma unroll
            for (int j = 0; j < 4; j++)
                acc[i][j] = __builtin_amdgcn_mfma_f32_16x16x32_bf16(af[i], bf[j], acc[i][j], 0, 0, 0);
        __syncthreads();
    }

    float* outf = (float*)outv + (size_t)z * oZ;
    u16* outh = (u16*)outv + (size_t)z * oZ;
#pragma unroll
    for (int i = 0; i < 4; i++) {
#pragma unroll
        for (int r = 0; r < 4; r++) {
            int row = m0 + wm + i * 16 + quad * 4 + r;
            if (row >= M) continue;
#pragma unroll
            for (int j = 0; j < 4; j++) {
                int col = n0 + wn + j * 16 + l16;
                if (col >= N) continue;
                float v = acc[i][j][r] + (BIASM ? bias[row] : bias[col]);
                if (relu) v = fmaxf(v, 0.f);
                if (ADD) v += add[(size_t)row * ldo + col];
                if (OUTF32) outf[(size_t)row * ldo + col] = v;
                else        outh[(size_t)row * ldo + col] = f2bf(v);
            }
        }
    }
}

// ---------------------------------------------------------------------------
// fp32 64x64 GEMM (side-chain only): out = A@B + bias (bias by col).
// ---------------------------------------------------------------------------
__global__ __launch_bounds__(256) void k_sgemm(
    const float* __restrict__ A, const float* __restrict__ Bm,
    const float* __restrict__ bias, float* __restrict__ out, int M) {
    __shared__ __align__(16) float As[16][68];
    __shared__ __align__(16) float Bs[16][68];
    const int tid = threadIdx.x;
    const int m0 = blockIdx.y * 64, n0 = blockIdx.x * 64;
    const int tm = tid >> 4, tn = tid & 15;
    const int kA = tid >> 4, mA = (tid << 2) & 63;
    const int mN = tid & 63, kq = tid >> 6;
    float acc[4][4] = {};
    for (int kt = 0; kt < 256; kt += 16) {
        int gm = m0 + mN;
        float4 u = {0.f, 0.f, 0.f, 0.f};
        if (gm < M) u = *(const float4*)(A + (size_t)gm * 256 + kt + (kq << 2));
        As[(kq << 2) + 0][mN] = u.x; As[(kq << 2) + 1][mN] = u.y;
        As[(kq << 2) + 2][mN] = u.z; As[(kq << 2) + 3][mN] = u.w;
        {
            float4 b = *(const float4*)(Bm + (size_t)(kt + kA) * 256 + n0 + mA);
            Bs[kA][mA + 0] = b.x; Bs[kA][mA + 1] = b.y;
            Bs[kA][mA + 2] = b.z; Bs[kA][mA + 3] = b.w;
        }
        __syncthreads();
#pragma unroll
        for (int k = 0; k < 16; k++) {
            const float4 av = *(const float4*)(&As[k][tm << 2]);
            const float4 bv = *(const float4*)(&Bs[k][tn << 2]);
            float ar[4] = {av.x, av.y, av.z, av.w};
            float br[4] = {bv.x, bv.y, bv.z, bv.w};
#pragma unroll
            for (int i = 0; i < 4; i++)
#pragma unroll
                for (int j = 0; j < 4; j++) acc[i][j] = fmaf(ar[i], br[j], acc[i][j]);
        }
        __syncthreads();
    }
#pragma unroll
    for (int i = 0; i < 4; i++) {
        int row = m0 + (tm << 2) + i;
        if (row >= M) continue;
        float4 o4;
        o4.x = acc[i][0] + bias[n0 + (tn << 2) + 0];
        o4.y = acc[i][1] + bias[n0 + (tn << 2) + 1];
        o4.z = acc[i][2] + bias[n0 + (tn << 2) + 2];
        o4.w = acc[i][3] + bias[n0 + (tn << 2) + 3];
        *(float4*)(out + (size_t)row * 256 + n0 + (tn << 2)) = o4;
    }
}

// LayerNorm+relu in-place, bf16 rows of 256; l = row/3600 (0..2 per launch).
__global__ __launch_bounds__(256) void k_lnb(
    u16* __restrict__ buf, const float* __restrict__ g, const float* __restrict__ be) {
    int tid = threadIdx.x, wid = tid >> 6, lane = tid & 63;
    int row = blockIdx.x * 4 + wid;
    int l = row / 3600;
    size_t base = (size_t)row * 256 + lane;
    float v[4];
#pragma unroll
    for (int i = 0; i < 4; i++) v[i] = bf2f(buf[base + (i << 6)]);
    float s = v[0] + v[1] + v[2] + v[3];
    for (int off = 32; off; off >>= 1) s += __shfl_down(s, off);
    s = __shfl(s, 0);
    float mean = s * (1.f / 256.f);
    float d[4], q = 0.f;
#pragma unroll
    for (int i = 0; i < 4; i++) { d[i] = v[i] - mean; q += d[i] * d[i]; }
    for (int off = 32; off; off >>= 1) q += __shfl_down(q, off);
    q = __shfl(q, 0);
    float rstd = rsqrtf(q * (1.f / 256.f) + 1e-5f);
#pragma unroll
    for (int i = 0; i < 4; i++) {
        int c = lane + (i << 6);
        buf[base + (i << 6)] = f2bf(fmaxf(d[i] * rstd * g[l * 256 + c] + be[l * 256 + c], 0.f));
    }
}

// fp32 LayerNorm+relu in-place, rows of 256 (side-chain; no layer offset).
__global__ __launch_bounds__(256) void k_ln5(
    float* __restrict__ buf, const float* __restrict__ g, const float* __restrict__ be) {
    int tid = threadIdx.x, wid = tid >> 6, lane = tid & 63;
    int row = blockIdx.x * 4 + wid;
    size_t base = (size_t)row * 256 + lane;
    float v[4];
#pragma unroll
    for (int i = 0; i < 4; i++) v[i] = buf[base + (i << 6)];
    float s = v[0] + v[1] + v[2] + v[3];
    for (int off = 32; off; off >>= 1) s += __shfl_down(s, off);
    s = __shfl(s, 0);
    float mean = s * (1.f / 256.f);
    float d[4], q = 0.f;
#pragma unroll
    for (int i = 0; i < 4; i++) { d[i] = v[i] - mean; q += d[i] * d[i]; }
    for (int off = 32; off; off >>= 1) q += __shfl_down(q, off);
    q = __shfl(q, 0);
    float rstd = rsqrtf(q * (1.f / 256.f) + 1e-5f);
#pragma unroll
    for (int i = 0; i < 4; i++) {
        int c = lane + (i << 6);
        buf[base + (i << 6)] = fmaxf(d[i] * rstd * g[c] + be[c], 0.f);
    }
}

// cls head: bf16 h2 (z layers, layer = lbase+z) -> all_cls fp32
__global__ __launch_bounds__(320) void k_heads_cls(
    const u16* __restrict__ hc, const float* __restrict__ wc, const float* __restrict__ bc,
    float* __restrict__ ocls, int lbase) {
    __shared__ u16 sh[32][256];
    int z = blockIdx.z, l = lbase + z, tb = blockIdx.x * 32, tid = threadIdx.x;
    for (int i = tid; i < 8192; i += 320) {
        int rr = i >> 8, k = i & 255;
        int tok = tb + rr;
        sh[rr][k] = (tok < 3600) ? hc[(size_t)(z * 3600 + tok) * 256 + k] : (u16)0;
    }
    __syncthreads();
    int tl = tid / 10, o = tid - tl * 10;
    const float* w = wc + l * 2560 + o;
    float ac = 0.f;
    for (int k = 0; k < 256; k++) ac += bf2f(sh[tl][k]) * w[k * 10];
    ac += bc[l * 10 + o];
    int tok = tb + tl;
    if (tok < 3600) ocls[(size_t)(l * 3600 + tok) * 10 + o] = ac;
}

// reg head + reg3 (first 3 coords) when layer == 5
__global__ __launch_bounds__(320) void k_heads_reg(
    const u16* __restrict__ hr, const float* __restrict__ wr, const float* __restrict__ br,
    float* __restrict__ oreg, float* __restrict__ reg3, int lbase) {
    __shared__ u16 sh[32][256];
    int z = blockIdx.z, l = lbase + z, tb = blockIdx.x * 32, tid = threadIdx.x;
    for (int i = tid; i < 8192; i += 320) {
        int rr = i >> 8, k = i & 255;
        int tok = tb + rr;
        sh[rr][k] = (tok < 3600) ? hr[(size_t)(z * 3600 + tok) * 256 + k] : (u16)0;
    }
    __syncthreads();
    int tl = tid / 10, o = tid - tl * 10;
    const float* w = wr + l * 2560 + o;
    float ar = 0.f;
    for (int k = 0; k < 256; k++) ar += bf2f(sh[tl][k]) * w[k * 10];
    ar += br[l * 10 + o];
    int tok = tb + tl;
    if (tok < 3600) {
        oreg[(size_t)(l * 3600 + tok) * 10 + o] = ar;
        if (l == 5 && o < 3) reg3[tok * 3 + o] = ar;
    }
}

// fp32 score (side-chain): h2f @ cls_w3[5] + b3 -> max over classes
__global__ __launch_bounds__(320) void k_score(
    const float* __restrict__ h2, const float* __restrict__ wc, const float* __restrict__ bc,
    float* __restrict__ score) {
    __shared__ float sh[32][256];
    __shared__ float clsv[32][10];
    int tb = blockIdx.x * 32, tid = threadIdx.x;
    for (int i = tid; i < 8192; i += 320) {
        int rr = i >> 8, k = i & 255;
        int tok = tb + rr;
        sh[rr][k] = (tok < 3600) ? h2[(size_t)tok * 256 + k] : 0.f;
    }
    __syncthreads();
    int tl = tid / 10, o = tid - tl * 10;
    const float* w = wc + 5 * 2560 + o;
    float ac = 0.f;
    for (int k = 0; k < 256; k++) ac += sh[tl][k] * w[k * 10];
    ac += bc[5 * 10 + o];
    int tok = tb + tl;
    if (tok < 3600) clsv[tl][o] = ac;
    __syncthreads();
    if (tid < 32 && tb + tid < 3600) {
        float m = clsv[tid][0];
#pragma unroll
        for (int c = 1; c < 10; c++) m = fmaxf(m, clsv[tid][c]);
        score[tb + tid] = m;  // max-logit == monotone proxy of max-sigmoid
    }
}

// exact top-k(256) ranks, jax.lax.top_k tie semantics
__global__ __launch_bounds__(1024) void k_sel(
    const float* __restrict__ score, int* __restrict__ sel) {
    __shared__ float sc[900];
    int b = blockIdx.x, tid = threadIdx.x;
    for (int i = tid; i < 900; i += 1024) sc[i] = score[b * 900 + i];
    __syncthreads();
    if (tid < 900) {
        float s = sc[tid];
        int r = 0;
        for (int j = 0; j < 900; j++) {
            float sj = sc[j];
            r += ((sj > s) || (sj == s && j < tid)) ? 1 : 0;
        }
        if (r < 256) sel[b * 256 + r] = tid;
    }
}

__global__ __launch_bounds__(256) void k_gather(
    const int* __restrict__ sel, const float* __restrict__ reg3,
    const float* __restrict__ od, float* __restrict__ oe, float* __restrict__ orr) {
    int b = blockIdx.y;
    int r = blockIdx.x * 4 + (threadIdx.x >> 6);
    int lane = threadIdx.x & 63;
    int q = sel[b * 256 + r];
    const float4* src = (const float4*)(od + (size_t)((20 + b) * 900 + q) * 256);
    float4* dst = (float4*)(oe + (size_t)(b * 512 + r) * 256);
    dst[lane] = src[lane];
    if (lane == 0) {
#pragma unroll
        for (int kk = 0; kk < 3; kk++) {
            float v = reg3[(b * 900 + q) * 3 + kk];
            float lo = (kk == 2) ? -5.0f : -51.2f;
            float rng = (kk == 2) ? 8.0f : 102.4f;
            orr[(size_t)(b * 512 + r) * 3 + kk] = fminf(fmaxf((v - lo) / rng, 0.f), 1.f);
        }
    }
}

// ---------------------------------------------------------------------------
extern "C" void kernel_launch(void* const* d_in, const int* in_sizes, int n_in,
                              void* d_out, int out_size, void* d_ws, size_t ws_size,
                              hipStream_t stream) {
    const float* feat   = (const float*)d_in[0];
    const float* l2i    = (const float*)d_in[1];
    const float* prev   = (const float*)d_in[2];
    const float* meme   = (const float*)d_in[3];
    const float* memr   = (const float*)d_in[4];
    const float* memt   = (const float*)d_in[5];
    const float* od     = (const float*)d_in[6];
    const float* rp     = (const float*)d_in[7];
    const float* ip_w   = (const float*)d_in[8];
    const float* ip_b   = (const float*)d_in[9];
    const float* pe_w1  = (const float*)d_in[10];
    const float* pe_b1  = (const float*)d_in[11];
    const float* pe_w2  = (const float*)d_in[12];
    const float* pe_b2  = (const float*)d_in[13];
    const float* ap_w1  = (const float*)d_in[14];
    const float* ap_b1  = (const float*)d_in[15];
    const float* ap_w2  = (const float*)d_in[16];
    const float* ap_b2  = (const float*)d_in[17];
    const float* qe_w1  = (const float*)d_in[18];
    const float* qe_b1  = (const float*)d_in[19];
    const float* qe_w2  = (const float*)d_in[20];
    const float* qe_b2  = (const float*)d_in[21];
    const float* te_w1  = (const float*)d_in[22];
    const float* te_b1  = (const float*)d_in[23];
    const float* te_w2  = (const float*)d_in[24];
    const float* te_b2  = (const float*)d_in[25];
    const float* cls_w1 = (const float*)d_in[26];
    const float* cls_b1 = (const float*)d_in[27];
    const float* cls_g1 = (const float*)d_in[28];
    const float* cls_be1= (const float*)d_in[29];
    const float* cls_w2 = (const float*)d_in[30];
    const float* cls_b2 = (const float*)d_in[31];
    const float* cls_g2 = (const float*)d_in[32];
    const float* cls_be2= (const float*)d_in[33];
    const float* cls_w3 = (const float*)d_in[34];
    const float* cls_b3 = (const float*)d_in[35];
    const float* reg_w1 = (const float*)d_in[36];
    const float* reg_b1 = (const float*)d_in[37];
    const float* reg_w2 = (const float*)d_in[38];
    const float* reg_b2 = (const float*)d_in[39];
    const float* reg_w3 = (const float*)d_in[40];
    const float* reg_b3 = (const float*)d_in[41];

    float* o32    = (float*)d_out;
    float* o_cls  = o32;                 // [0, 216000)
    float* o_reg  = o32 + 216000;        // [216000, 432000)
    float* o_meme = o32 + 432000;        // [432000, 956288)
    float* o_memr = o32 + 956288;
    float* o_memt = o32 + 962432;
    float* o_pos  = o32 + 964480;        // [964480, 5289856)
    float* o_x    = o32 + 5289856;       // [5289856, 9615232)
    float* o_qp   = o32 + 9615232;
    float* o_te   = o32 + 9845632;       // [9845632, 10369920)
    float* o_cm   = o32 + 10369920;

    // ---- d_out-resident scratch (temporally dead at use time) ----
    u16*   h1b   = (u16*)(o32 + 432000);     // decoder h1, 6 layers bf16
    u16*   h2b   = (u16*)(o32 + 3196800);    // decoder h2
    float* h1f   = o32 + 432000;             // side-chain fp32 (after decoder)
    float* h2f   = o32 + 1353600;
    u16*   c3aT  = (u16*)(o32 + 432000);     // frustum [24][704][192] bf16 (PE phase)
    u16*   w1Tc  = (u16*)(o32 + 6100992);    // decoder weights bf16 [6][256][256]
    u16*   w1Tr  = (u16*)(o32 + 6297600);
    u16*   w2Tc  = (u16*)(o32 + 6494208);
    u16*   w2Tr  = (u16*)(o32 + 6690816);
    u16*   pe1T  = (u16*)(o32 + 6887424);    // [512][192] bf16
    u16*   pe2T  = (u16*)(o32 + 6936576);    // [256][512]
    u16*   ap1T  = (u16*)(o32 + 7034880);    // [256][256]
    u16*   ap2T  = (u16*)(o32 + 7067648);
    u16*   h1pe  = (u16*)(o32 + 7150592);    // PE h1 chunk [6][512][704] bf16
    float* sineb = o32 + 8231936;            // [256][704] fp32
    float* sinea = o32 + 8412160;
    u16*   hapb  = (u16*)(o32 + 8592384);    // [256][704] bf16
    // persistent tail in o_te (o_te written last):
    float* w_score = o32 + 9845632;          // 3600
    float* w_reg3  = o32 + 9849232;          // 10800
    float* w_inv   = o32 + 9860032;          // 384
    int*   w_sel   = (int*)(o32 + 9860416);  // 1024
    u16*   ipT     = (u16*)(o32 + 9861440);  // [256][256] bf16 (ip reads while writing o_x)

    k_inv<<<1, 32, 0, stream>>>(l2i, w_inv);

    // ---- weight prep (transpose + cvt to bf16 [N][K]) ----
    k_wtr4<<<dim3(8, 8, 24), 256, 0, stream>>>(cls_w1, reg_w1, cls_w2, reg_w2,
                                               w1Tc, w1Tr, w2Tc, w2Tr, 256, 256, 6);
    k_wtr4<<<dim3(16, 6, 1), 256, 0, stream>>>(pe_w1, pe_w1, pe_w1, pe_w1,
                                               pe1T, pe1T, pe1T, pe1T, 192, 512, 1);
    k_wtr4<<<dim3(8, 16, 1), 256, 0, stream>>>(pe_w2, pe_w2, pe_w2, pe_w2,
                                               pe2T, pe2T, pe2T, pe2T, 512, 256, 1);
    k_wtr4<<<dim3(8, 8, 3), 256, 0, stream>>>(ip_w, ap_w1, ap_w2, ap_w2,
                                              ipT, ap1T, ap2T, ap2T, 256, 256, 1);

    // ---- decoder, 2 chunks of (3 cls + 3 reg) layers, bf16 MFMA ----
    for (int c = 0; c < 2; c++) {
        k_mfma<1, 0, 0, 0, 0, 0><<<dim3(2, 29, 6), 256, 0, stream>>>(
            od + (size_t)c * 3 * 921600, w1Tc + (size_t)c * 3 * 65536, w1Tr + (size_t)c * 3 * 65536,
            cls_b1 + c * 768, reg_b1 + c * 768, nullptr, h1b,
            3600, 256, 256, 256, 256, 256, 921600, 65536, 256, 921600, 3, 3, 0);
        k_lnb<<<2700, 256, 0, stream>>>(h1b, cls_g1 + c * 768, cls_be1 + c * 768);
        k_mfma<0, 0, 0, 0, 0, 0><<<dim3(2, 29, 6), 256, 0, stream>>>(
            h1b, w2Tc + (size_t)c * 3 * 65536, w2Tr + (size_t)c * 3 * 65536,
            cls_b2 + c * 768, reg_b2 + c * 768, nullptr, h2b,
            3600, 256, 256, 256, 256, 256, 921600, 65536, 256, 921600, 3, 3, 1);
        k_lnb<<<2700, 256, 0, stream>>>(h2b, cls_g2 + c * 768, cls_be2 + c * 768);
        k_heads_cls<<<dim3(113, 1, 3), 320, 0, stream>>>(h2b, cls_w3, cls_b3, o_cls, c * 3);
        k_heads_reg<<<dim3(113, 1, 3), 320, 0, stream>>>(h2b + (size_t)3 * 921600,
                                                         reg_w3, reg_b3, o_reg, w_reg3, c * 3);
    }

    // ---- fp32 side-chain: exact layer-5 cls scores for top-k ordering ----
    k_sgemm<<<dim3(4, 57), 256, 0, stream>>>(od + (size_t)5 * 921600, cls_w1 + 5 * 65536,
                                             cls_b1 + 5 * 256, h1f, 3600);
    k_ln5<<<900, 256, 0, stream>>>(h1f, cls_g1 + 5 * 256, cls_be1 + 5 * 256);
    k_sgemm<<<dim3(4, 57), 256, 0, stream>>>(h1f, cls_w2 + 5 * 65536, cls_b2 + 5 * 256, h2f, 3600);
    k_ln5<<<900, 256, 0, stream>>>(h2f, cls_g2 + 5 * 256, cls_be2 + 5 * 256);
    k_score<<<113, 320, 0, stream>>>(h2f, cls_w3, cls_b3, w_score);

    // ---- PE phase ----
    k_frustum<<<66, 256, 0, stream>>>(w_inv, c3aT, o_cm);
    k_sinebase<<<704, 256, 0, stream>>>(sineb);
    k_mfma<0, 1, 1, 0, 0, 1><<<dim3(6, 2, 1), 256, 0, stream>>>(
        ap1T, sineb, sineb, ap_b1, ap_b1, nullptr, hapb,
        256, 704, 256, 256, 704, 704, 0, 0, 0, 0, 99, 0, 0);
    k_mfma<0, 1, 0, 1, 0, 1><<<dim3(6, 2, 1), 256, 0, stream>>>(
        ap2T, hapb, hapb, ap_b2, ap_b2, nullptr, sinea,
        256, 704, 256, 256, 704, 704, 0, 0, 0, 0, 99, 99, 0);
    // PETR MLP in REVERSE chunk order (o_pos writes clobber only consumed c3aT)
    for (int c = 3; c >= 0; c--) {
        k_mfma<0, 0, 0, 0, 0, 1><<<dim3(6, 4, 6), 256, 0, stream>>>(
            pe1T, c3aT + (size_t)c * 6 * 135168, c3aT, pe_b1, pe_b1, nullptr, h1pe,
            512, 704, 192, 192, 192, 704, 0, 135168, 0, 360448, 99, 0, 0);
        k_mfma<0, 1, 0, 1, 1, 1><<<dim3(6, 2, 6), 256, 0, stream>>>(
            pe2T, h1pe, h1pe, pe_b2, pe_b2, sinea, o_pos + (size_t)c * 6 * 180224,
            256, 704, 512, 512, 704, 704, 0, 360448, 0, 180224, 99, 99, 0);
    }
    // input projection last (overwrites all o_x scratch; ipT lives in o_te tail)
    k_mfma<0, 1, 1, 1, 0, 1><<<dim3(6, 2, 24), 256, 0, stream>>>(
        ipT, feat, feat, ip_b, ip_b, nullptr, o_x,
        256, 704, 256, 256, 704, 704, 0, 180224, 0, 180224, 99, 99, 0);

    // ---- memory outputs ----
    k_memtail<<<1024, 256, 0, stream>>>(meme, memr, memt, prev, o_meme, o_memr, o_memt);
    k_sel<<<4, 1024, 0, stream>>>(w_score, w_sel);
    k_gather<<<dim3(64, 4), 256, 0, stream>>>(w_sel, w_reg3, od, o_meme, o_memr);

    // ---- small embeddings last (o_te tail held score/reg3/inv/sel/ipT) ----
    k_time<<<256, 256, 0, stream>>>(memt, prev, te_w1, te_b1, te_w2, te_b2, o_te);
    k_query<<<225, 256, 0, stream>>>(rp, qe_w1, qe_b1, qe_w2, qe_b2, o_qp);
}

// Round 7
// 618.154 us; speedup vs baseline: 1.5740x; 1.5740x over previous
//
#include <hip/hip_runtime.h>
#include <math.h>

// ---------------------------------------------------------------------------
// StreamPETRHeadLite forward. fp32 I/O; bulk GEMMs via pipelined bf16 MFMA
// (64x128 tiles, register prefetch); fp32 side-chain keeps exact top-k order.
// Zero d_ws usage — scratch lives in temporally-dead regions of d_out.
// ---------------------------------------------------------------------------

typedef unsigned short u16;
typedef __attribute__((ext_vector_type(8))) short short8v;   // 8 bf16
typedef __attribute__((ext_vector_type(4))) float f32x4;

#define DI __device__ __forceinline__
DI u16 f2bf(float f) {
    unsigned x = __float_as_uint(f);
    return (u16)((x + 0x7fffu + ((x >> 16) & 1u)) >> 16);  // RNE
}
DI float bf2f(u16 u) { return __uint_as_float(((unsigned)u) << 16); }

#define TWO_PI_F 6.283185307179586f

// ---------------------------------------------------------------------------
__global__ void k_inv(const float* __restrict__ l2i, float* __restrict__ out) {
    int t = threadIdx.x;
    if (t >= 24) return;
    float a[4][8];
    for (int i = 0; i < 4; i++)
        for (int j = 0; j < 4; j++) {
            a[i][j] = l2i[t * 16 + i * 4 + j];
            a[i][4 + j] = (i == j) ? 1.f : 0.f;
        }
    for (int c = 0; c < 4; c++) {
        int p = c; float mv = fabsf(a[c][c]);
        for (int r = c + 1; r < 4; r++) {
            float v = fabsf(a[r][c]);
            if (v > mv) { mv = v; p = r; }
        }
        if (p != c)
            for (int j = 0; j < 8; j++) { float tmp = a[c][j]; a[c][j] = a[p][j]; a[p][j] = tmp; }
        float ip = 1.f / a[c][c];
        for (int j = 0; j < 8; j++) a[c][j] *= ip;
        for (int r = 0; r < 4; r++) {
            if (r == c) continue;
            float f = a[r][c];
            for (int j = 0; j < 8; j++) a[r][j] -= f * a[c][j];
        }
    }
    for (int i = 0; i < 4; i++)
        for (int j = 0; j < 4; j++)
            out[t * 16 + i * 4 + j] = a[i][4 + j];
}

__global__ __launch_bounds__(256) void k_memtail(
    const float* __restrict__ me, const float* __restrict__ mr, const float* __restrict__ mt,
    const float* __restrict__ prev,
    float* __restrict__ oe, float* __restrict__ orr, float* __restrict__ ot) {
    int b = blockIdx.x >> 8, j = blockIdx.x & 255, o = threadIdx.x;
    float pv = prev[b];
    oe[(size_t)(b * 512 + 256 + j) * 256 + o] = me[(size_t)(b * 512 + j) * 256 + o] * pv;
    if (o < 3)
        orr[(size_t)(b * 512 + 256 + j) * 3 + o] = mr[(size_t)(b * 512 + j) * 3 + o] * pv;
    if (o == 0) {
        ot[b * 512 + 256 + j] = mt[b * 512 + j] * pv + pv;
        ot[b * 512 + j] = 0.f;
    }
}

// frustum: wave per pixel (lane = depth bin); c3aT [bn*704+p][192] bf16
__global__ __launch_bounds__(256) void k_frustum(
    const float* __restrict__ inv, u16* __restrict__ c3aT, float* __restrict__ cm) {
    int pix = blockIdx.x * 4 + (threadIdx.x >> 6);
    int d = threadIdx.x & 63;
    int bn = pix / 704, p = pix - bn * 704;
    int h = p / 44, w = p - h * 44;
    const float* M = inv + bn * 16;
    float cw = w * 16.0f, ch = h * 16.0f;
    const float bin = (61.2f - 1.0f) / (64.0f * 65.0f);
    float cd = 1.0f + (bin * d) * (d + 1.0f);
    float xx = cw * cd, yy = ch * cd;
    float px = M[0] * xx + M[1] * yy + M[2] * cd + M[3];
    float py = M[4] * xx + M[5] * yy + M[6] * cd + M[7];
    float pz = M[8] * xx + M[9] * yy + M[10] * cd + M[11];
    float c[3];
    c[0] = (px + 61.2f) * (1.f / 122.4f);
    c[1] = (py + 61.2f) * (1.f / 122.4f);
    c[2] = (pz + 10.0f) * (1.f / 20.0f);
    u16* o = c3aT + (size_t)pix * 192 + d * 3;
    int cnt = 0;
#pragma unroll
    for (int i = 0; i < 3; i++) {
        cnt += ((c[i] > 1.0f) || (c[i] < 0.0f)) ? 1 : 0;
        float cc = fminf(fmaxf(c[i], 0.f), 1.f);
        float num = fmaxf(cc, 1e-5f);
        float den = fmaxf(1.0f - cc, 1e-5f);
        o[i] = f2bf(logf(num / den));
    }
    for (int off = 32; off; off >>= 1) cnt += __shfl_down(cnt, off);
    if (d == 0) cm[pix] = (cnt > 32) ? 1.f : 0.f;
}

__global__ __launch_bounds__(256) void k_sinebase(float* __restrict__ out) {
    int idx = blockIdx.x * 256 + threadIdx.x;
    if (idx >= 256 * 704) return;
    int c = idx / 704, p = idx - c * 704;
    int h = p / 44, w = p - h * 44;
    float pos = (c < 128) ? (h + 1) * (TWO_PI_F / (16.0f + 1e-6f))
                          : (w + 1) * (TWO_PI_F / (44.0f + 1e-6f));
    int cc = c & 127, k = cc >> 1;
    float dt = powf(10000.f, k * (1.f / 64.f));
    float arg = pos / dt;
    out[idx] = (cc & 1) ? cosf(arg) : sinf(arg);
}

__global__ __launch_bounds__(256) void k_time(
    const float* __restrict__ ts, const float* __restrict__ prev,
    const float* __restrict__ w1, const float* __restrict__ b1,
    const float* __restrict__ w2, const float* __restrict__ b2, float* __restrict__ out) {
    __shared__ float fin[8][128];
    __shared__ float h1[8][256];
    int tid = threadIdx.x, r0 = blockIdx.x * 8;
    for (int i = tid; i < 1024; i += 256) {
        int r = i >> 7, f = i & 127;
        int row = r0 + r, b = row >> 9;
        float pv = prev[b];
        float mt = ts[row] * pv + pv;
        float dt = powf(10000.f, (f >> 1) * (1.f / 64.f));
        float arg = mt * TWO_PI_F / dt;
        fin[r][f] = (f & 1) ? cosf(arg) : sinf(arg);
    }
    __syncthreads();
    int j = tid;
    float acc[8] = {};
    for (int k = 0; k < 128; k++) {
        float wv = w1[k * 256 + j];
#pragma unroll
        for (int r = 0; r < 8; r++) acc[r] += fin[r][k] * wv;
    }
    float bb = b1[j];
#pragma unroll
    for (int r = 0; r < 8; r++) h1[r][j] = fmaxf(acc[r] + bb, 0.f);
    __syncthreads();
    float a2[8] = {};
    for (int k = 0; k < 256; k++) {
        float wv = w2[k * 256 + j];
#pragma unroll
        for (int r = 0; r < 8; r++) a2[r] += h1[r][k] * wv;
    }
    float b2v = b2[j];
#pragma unroll
    for (int r = 0; r < 8; r++) out[(size_t)(r0 + r) * 256 + j] = a2[r] + b2v;
}

__global__ __launch_bounds__(256) void k_query(
    const float* __restrict__ rp, const float* __restrict__ w1, const float* __restrict__ b1,
    const float* __restrict__ w2, const float* __restrict__ b2, float* __restrict__ out) {
    __shared__ float fin[4][384];
    __shared__ float h1[4][256];
    int tid = threadIdx.x, r0 = blockIdx.x * 4;
    for (int i = tid; i < 1536; i += 256) {
        int r = i / 384, f = i - r * 384;
        int row = r0 + r;
        int seg = f >> 7, ff = f & 127;
        int cidx = (seg == 0) ? 1 : ((seg == 1) ? 0 : 2);
        float rv = rp[row * 3 + cidx];
        float dt = powf(10000.f, (ff >> 1) * (1.f / 64.f));
        float arg = rv * TWO_PI_F / dt;
        fin[r][f] = (ff & 1) ? cosf(arg) : sinf(arg);
    }
    __syncthreads();
    int j = tid;
    float acc[4] = {};
    for (int k = 0; k < 384; k++) {
        float wv = w1[k * 256 + j];
#pragma unroll
        for (int r = 0; r < 4; r++) acc[r] += fin[r][k] * wv;
    }
    float bb = b1[j];
#pragma unroll
    for (int r = 0; r < 4; r++) h1[r][j] = fmaxf(acc[r] + bb, 0.f);
    __syncthreads();
    float a2[4] = {};
    for (int k = 0; k < 256; k++) {
        float wv = w2[k * 256 + j];
#pragma unroll
        for (int r = 0; r < 4; r++) a2[r] += h1[r][k] * wv;
    }
    float b2v = b2[j];
#pragma unroll
    for (int r = 0; r < 4; r++) out[(size_t)(r0 + r) * 256 + j] = a2[r] + b2v;
}

// ---------------------------------------------------------------------------
// Weight transpose+cvt: in [K][N] f32 -> out [N][K] bf16. Tensor = z/zper.
// ---------------------------------------------------------------------------
__global__ __launch_bounds__(256) void k_wtr4(
    const float* __restrict__ s0, const float* __restrict__ s1,
    const float* __restrict__ s2, const float* __restrict__ s3,
    u16* __restrict__ d0, u16* __restrict__ d1, u16* __restrict__ d2, u16* __restrict__ d3,
    int K, int N, int zper) {
    __shared__ float sh[32][33];
    int z = blockIdx.z, ti = z / zper, zz = z - ti * zper;
    const float* src = (ti == 0 ? s0 : ti == 1 ? s1 : ti == 2 ? s2 : s3) + (size_t)zz * K * N;
    u16* dst = (ti == 0 ? d0 : ti == 1 ? d1 : ti == 2 ? d2 : d3) + (size_t)zz * K * N;
    int n0 = blockIdx.x * 32, k0 = blockIdx.y * 32;
    int tx = threadIdx.x & 31, ty = threadIdx.x >> 5;
#pragma unroll
    for (int r = 0; r < 4; r++)
        sh[ty + 8 * r][tx] = src[(size_t)(k0 + ty + 8 * r) * N + n0 + tx];
    __syncthreads();
#pragma unroll
    for (int r = 0; r < 4; r++)
        dst[(size_t)(n0 + ty + 8 * r) * K + k0 + tx] = f2bf(sh[tx][ty + 8 * r]);
}

// ---------------------------------------------------------------------------
// Pipelined bf16 MFMA GEMM: out[m][n] = sum_k A[m][k]*B[k][n] (+bias/relu/add)
// 64x128 block tile, BK=32, 256 threads = 4 waves (2m x 2n of 32x64), 2x4
// frags of v_mfma_f32_16x16x32_bf16. Register prefetch of next K-tile.
//   A: m-major [M][K]; AF32 selects fp32(cvt)/bf16.
//   B: BTRANS=0 -> [N][K] bf16 (pre-transposed); BTRANS=1 -> [K][N] (BF32 dtype)
//   OUTF32: out dtype. ADD: += add[row*ldo+col] (fp32, shared over z).
//   BIASM: bias by m (1) / n (0). relu iff z >= zrelu.
//   Dual-B: z < zsplit -> B1/bias1 (zz=z), else B2/bias2 (zz=z-zsplit).
// ---------------------------------------------------------------------------
template <int AF32, int BTRANS, int BF32, int OUTF32, int ADD, int BIASM>
__global__ __launch_bounds__(256) void k_mfma(
    const void* __restrict__ Av, const void* __restrict__ B1v, const void* __restrict__ B2v,
    const float* __restrict__ bias1, const float* __restrict__ bias2,
    const float* __restrict__ add, void* __restrict__ outv,
    int M, int N, int K, int lda, int ldb, int ldo,
    long aZ, long bZ, long biasZ, long oZ, int zsplit, int zrelu, int aFull) {
    __shared__ __align__(16) u16 As[64][40];
    __shared__ __align__(16) u16 Bs[128][40];
    const int tid = threadIdx.x;
    const int z = blockIdx.z;
    const int zz = (z < zsplit) ? z : z - zsplit;
    const void* Bv = (z < zsplit) ? B1v : B2v;
    const float* bias = ((z < zsplit) ? bias1 : bias2) + (size_t)zz * biasZ;
    const bool relu = (z >= zrelu);
    const long aOff = (long)(aFull ? z : zz) * aZ;
    const long bOff = (long)zz * bZ;
    const int m0 = blockIdx.y * 64, n0 = blockIdx.x * 128;
    const int wave = tid >> 6, lane = tid & 63, quad = lane >> 4, l16 = lane & 15;
    const int wm = (wave >> 1) * 32, wn = (wave & 1) * 64;
    const int ar = tid & 63, ak = (tid >> 6) << 3;     // A staging: row, k-seg(8)
    const int br = tid & 127, bk = (tid >> 7) << 4;    // B staging: row, k-half(16)
    f32x4 acc[2][4] = {};

    float pAf[8]; uint4 pAu = make_uint4(0, 0, 0, 0);
    float pBf[16]; u16 pBh[16];
    uint4 pBu0 = make_uint4(0, 0, 0, 0), pBu1 = make_uint4(0, 0, 0, 0);

    auto loadA = [&](int kt) {
        int gm = m0 + ar;
        if (AF32) {
#pragma unroll
            for (int q = 0; q < 8; q++) pAf[q] = 0.f;
            if (gm < M) {
                const float* ap = (const float*)Av + aOff + (size_t)gm * lda + kt + ak;
                float4 f0 = *(const float4*)ap;
                float4 f1 = *(const float4*)(ap + 4);
                pAf[0] = f0.x; pAf[1] = f0.y; pAf[2] = f0.z; pAf[3] = f0.w;
                pAf[4] = f1.x; pAf[5] = f1.y; pAf[6] = f1.z; pAf[7] = f1.w;
            }
        } else {
            pAu = make_uint4(0, 0, 0, 0);
            if (gm < M)
                pAu = *(const uint4*)((const u16*)Av + aOff + (size_t)gm * lda + kt + ak);
        }
    };
    auto storeA = [&]() {
        if (AF32) {
            uint4 u;
            u.x = f2bf(pAf[0]) | ((unsigned)f2bf(pAf[1]) << 16);
            u.y = f2bf(pAf[2]) | ((unsigned)f2bf(pAf[3]) << 16);
            u.z = f2bf(pAf[4]) | ((unsigned)f2bf(pAf[5]) << 16);
            u.w = f2bf(pAf[6]) | ((unsigned)f2bf(pAf[7]) << 16);
            *(uint4*)&As[ar][ak] = u;
        } else {
            *(uint4*)&As[ar][ak] = pAu;
        }
    };
    auto loadB = [&](int kt) {
        int gn = n0 + br;
        if (!BTRANS) {
            pBu0 = make_uint4(0, 0, 0, 0);
            pBu1 = make_uint4(0, 0, 0, 0);
            if (gn < N) {
                const u16* bp = (const u16*)Bv + bOff + (size_t)gn * ldb + kt + bk;
                pBu0 = *(const uint4*)bp;
                pBu1 = *(const uint4*)(bp + 8);
            }
        } else if (BF32) {
#pragma unroll
            for (int kk = 0; kk < 16; kk++)
                pBf[kk] = (gn < N) ? ((const float*)Bv + bOff)[(size_t)(kt + bk + kk) * ldb + gn]
                                   : 0.f;
        } else {
#pragma unroll
            for (int kk = 0; kk < 16; kk++)
                pBh[kk] = (gn < N) ? ((const u16*)Bv + bOff)[(size_t)(kt + bk + kk) * ldb + gn]
                                   : (u16)0;
        }
    };
    auto storeB = [&]() {
        if (!BTRANS) {
            *(uint4*)&Bs[br][bk] = pBu0;
            *(uint4*)&Bs[br][bk + 8] = pBu1;
        } else {
            u16 t[16];
#pragma unroll
            for (int kk = 0; kk < 16; kk++) t[kk] = BF32 ? f2bf(pBf[kk]) : pBh[kk];
            uint4 u0, u1;
            u0.x = t[0] | ((unsigned)t[1] << 16);
            u0.y = t[2] | ((unsigned)t[3] << 16);
            u0.z = t[4] | ((unsigned)t[5] << 16);
            u0.w = t[6] | ((unsigned)t[7] << 16);
            u1.x = t[8] | ((unsigned)t[9] << 16);
            u1.y = t[10] | ((unsigned)t[11] << 16);
            u1.z = t[12] | ((unsigned)t[13] << 16);
            u1.w = t[14] | ((unsigned)t[15] << 16);
            *(uint4*)&Bs[br][bk] = u0;
            *(uint4*)&Bs[br][bk + 8] = u1;
        }
    };

    loadA(0); loadB(0);
    for (int kt = 0; kt < K; kt += 32) {
        storeA(); storeB();
        __syncthreads();
        if (kt + 32 < K) { loadA(kt + 32); loadB(kt + 32); }  // prefetch in flight
        short8v af[2], bfr[4];
#pragma unroll
        for (int i = 0; i < 2; i++) af[i] = *(const short8v*)&As[wm + i * 16 + l16][quad * 8];
#pragma unroll
        for (int j = 0; j < 4; j++) bfr[j] = *(const short8v*)&Bs[wn + j * 16 + l16][quad * 8];
#pragma unroll
        for (int i = 0; i < 2; i++)
#pragma unroll
            for (int j = 0; j < 4; j++)
                acc[i][j] = __builtin_amdgcn_mfma_f32_16x16x32_bf16(af[i], bfr[j], acc[i][j], 0, 0, 0);
        __syncthreads();
    }

    float* outf = (float*)outv + (size_t)z * oZ;
    u16* outh = (u16*)outv + (size_t)z * oZ;
#pragma unroll
    for (int i = 0; i < 2; i++) {
#pragma unroll
        for (int r = 0; r < 4; r++) {
            int row = m0 + wm + i * 16 + quad * 4 + r;
            if (row >= M) continue;
#pragma unroll
            for (int j = 0; j < 4; j++) {
                int col = n0 + wn + j * 16 + l16;
                if (col >= N) continue;
                float v = acc[i][j][r] + (BIASM ? bias[row] : bias[col]);
                if (relu) v = fmaxf(v, 0.f);
                if (ADD) v += add[(size_t)row * ldo + col];
                if (OUTF32) outf[(size_t)row * ldo + col] = v;
                else        outh[(size_t)row * ldo + col] = f2bf(v);
            }
        }
    }
}

// ---------------------------------------------------------------------------
// fp32 64x64 GEMM (side-chain only): out = A@B + bias (bias by col).
// ---------------------------------------------------------------------------
__global__ __launch_bounds__(256) void k_sgemm(
    const float* __restrict__ A, const float* __restrict__ Bm,
    const float* __restrict__ bias, float* __restrict__ out, int M) {
    __shared__ __align__(16) float As[16][68];
    __shared__ __align__(16) float Bs[16][68];
    const int tid = threadIdx.x;
    const int m0 = blockIdx.y * 64, n0 = blockIdx.x * 64;
    const int tm = tid >> 4, tn = tid & 15;
    const int kA = tid >> 4, mA = (tid << 2) & 63;
    const int mN = tid & 63, kq = tid >> 6;
    float acc[4][4] = {};
    for (int kt = 0; kt < 256; kt += 16) {
        int gm = m0 + mN;
        float4 u = {0.f, 0.f, 0.f, 0.f};
        if (gm < M) u = *(const float4*)(A + (size_t)gm * 256 + kt + (kq << 2));
        As[(kq << 2) + 0][mN] = u.x; As[(kq << 2) + 1][mN] = u.y;
        As[(kq << 2) + 2][mN] = u.z; As[(kq << 2) + 3][mN] = u.w;
        {
            float4 b = *(const float4*)(Bm + (size_t)(kt + kA) * 256 + n0 + mA);
            Bs[kA][mA + 0] = b.x; Bs[kA][mA + 1] = b.y;
            Bs[kA][mA + 2] = b.z; Bs[kA][mA + 3] = b.w;
        }
        __syncthreads();
#pragma unroll
        for (int k = 0; k < 16; k++) {
            const float4 av = *(const float4*)(&As[k][tm << 2]);
            const float4 bv = *(const float4*)(&Bs[k][tn << 2]);
            float ar[4] = {av.x, av.y, av.z, av.w};
            float br[4] = {bv.x, bv.y, bv.z, bv.w};
#pragma unroll
            for (int i = 0; i < 4; i++)
#pragma unroll
                for (int j = 0; j < 4; j++) acc[i][j] = fmaf(ar[i], br[j], acc[i][j]);
        }
        __syncthreads();
    }
#pragma unroll
    for (int i = 0; i < 4; i++) {
        int row = m0 + (tm << 2) + i;
        if (row >= M) continue;
        float4 o4;
        o4.x = acc[i][0] + bias[n0 + (tn << 2) + 0];
        o4.y = acc[i][1] + bias[n0 + (tn << 2) + 1];
        o4.z = acc[i][2] + bias[n0 + (tn << 2) + 2];
        o4.w = acc[i][3] + bias[n0 + (tn << 2) + 3];
        *(float4*)(out + (size_t)row * 256 + n0 + (tn << 2)) = o4;
    }
}

// LayerNorm+relu in-place, bf16 rows of 256; l = row/3600 (0..5).
__global__ __launch_bounds__(256) void k_lnb(
    u16* __restrict__ buf, const float* __restrict__ g, const float* __restrict__ be) {
    int tid = threadIdx.x, wid = tid >> 6, lane = tid & 63;
    int row = blockIdx.x * 4 + wid;
    int l = row / 3600;
    size_t base = (size_t)row * 256 + lane;
    float v[4];
#pragma unroll
    for (int i = 0; i < 4; i++) v[i] = bf2f(buf[base + (i << 6)]);
    float s = v[0] + v[1] + v[2] + v[3];
    for (int off = 32; off; off >>= 1) s += __shfl_down(s, off);
    s = __shfl(s, 0);
    float mean = s * (1.f / 256.f);
    float d[4], q = 0.f;
#pragma unroll
    for (int i = 0; i < 4; i++) { d[i] = v[i] - mean; q += d[i] * d[i]; }
    for (int off = 32; off; off >>= 1) q += __shfl_down(q, off);
    q = __shfl(q, 0);
    float rstd = rsqrtf(q * (1.f / 256.f) + 1e-5f);
#pragma unroll
    for (int i = 0; i < 4; i++) {
        int c = lane + (i << 6);
        buf[base + (i << 6)] = f2bf(fmaxf(d[i] * rstd * g[l * 256 + c] + be[l * 256 + c], 0.f));
    }
}

// fp32 LayerNorm+relu in-place, rows of 256 (side-chain).
__global__ __launch_bounds__(256) void k_ln5(
    float* __restrict__ buf, const float* __restrict__ g, const float* __restrict__ be) {
    int tid = threadIdx.x, wid = tid >> 6, lane = tid & 63;
    int row = blockIdx.x * 4 + wid;
    size_t base = (size_t)row * 256 + lane;
    float v[4];
#pragma unroll
    for (int i = 0; i < 4; i++) v[i] = buf[base + (i << 6)];
    float s = v[0] + v[1] + v[2] + v[3];
    for (int off = 32; off; off >>= 1) s += __shfl_down(s, off);
    s = __shfl(s, 0);
    float mean = s * (1.f / 256.f);
    float d[4], q = 0.f;
#pragma unroll
    for (int i = 0; i < 4; i++) { d[i] = v[i] - mean; q += d[i] * d[i]; }
    for (int off = 32; off; off >>= 1) q += __shfl_down(q, off);
    q = __shfl(q, 0);
    float rstd = rsqrtf(q * (1.f / 256.f) + 1e-5f);
#pragma unroll
    for (int i = 0; i < 4; i++) {
        int c = lane + (i << 6);
        buf[base + (i << 6)] = fmaxf(d[i] * rstd * g[c] + be[c], 0.f);
    }
}

// cls head: bf16 h2 (z layers, layer = lbase+z) -> all_cls fp32
__global__ __launch_bounds__(320) void k_heads_cls(
    const u16* __restrict__ hc, const float* __restrict__ wc, const float* __restrict__ bc,
    float* __restrict__ ocls, int lbase) {
    __shared__ u16 sh[32][256];
    int z = blockIdx.z, l = lbase + z, tb = blockIdx.x * 32, tid = threadIdx.x;
    for (int i = tid; i < 8192; i += 320) {
        int rr = i >> 8, k = i & 255;
        int tok = tb + rr;
        sh[rr][k] = (tok < 3600) ? hc[(size_t)(z * 3600 + tok) * 256 + k] : (u16)0;
    }
    __syncthreads();
    int tl = tid / 10, o = tid - tl * 10;
    const float* w = wc + l * 2560 + o;
    float ac = 0.f;
    for (int k = 0; k < 256; k++) ac += bf2f(sh[tl][k]) * w[k * 10];
    ac += bc[l * 10 + o];
    int tok = tb + tl;
    if (tok < 3600) ocls[(size_t)(l * 3600 + tok) * 10 + o] = ac;
}

// reg head + reg3 (first 3 coords) when layer == 5
__global__ __launch_bounds__(320) void k_heads_reg(
    const u16* __restrict__ hr, const float* __restrict__ wr, const float* __restrict__ br,
    float* __restrict__ oreg, float* __restrict__ reg3, int lbase) {
    __shared__ u16 sh[32][256];
    int z = blockIdx.z, l = lbase + z, tb = blockIdx.x * 32, tid = threadIdx.x;
    for (int i = tid; i < 8192; i += 320) {
        int rr = i >> 8, k = i & 255;
        int tok = tb + rr;
        sh[rr][k] = (tok < 3600) ? hr[(size_t)(z * 3600 + tok) * 256 + k] : (u16)0;
    }
    __syncthreads();
    int tl = tid / 10, o = tid - tl * 10;
    const float* w = wr + l * 2560 + o;
    float ar = 0.f;
    for (int k = 0; k < 256; k++) ar += bf2f(sh[tl][k]) * w[k * 10];
    ar += br[l * 10 + o];
    int tok = tb + tl;
    if (tok < 3600) {
        oreg[(size_t)(l * 3600 + tok) * 10 + o] = ar;
        if (l == 5 && o < 3) reg3[tok * 3 + o] = ar;
    }
}

// fp32 score (side-chain): h2f @ cls_w3[5] + b3 -> max over classes
__global__ __launch_bounds__(320) void k_score(
    const float* __restrict__ h2, const float* __restrict__ wc, const float* __restrict__ bc,
    float* __restrict__ score) {
    __shared__ float sh[32][256];
    __shared__ float clsv[32][10];
    int tb = blockIdx.x * 32, tid = threadIdx.x;
    for (int i = tid; i < 8192; i += 320) {
        int rr = i >> 8, k = i & 255;
        int tok = tb + rr;
        sh[rr][k] = (tok < 3600) ? h2[(size_t)tok * 256 + k] : 0.f;
    }
    __syncthreads();
    int tl = tid / 10, o = tid - tl * 10;
    const float* w = wc + 5 * 2560 + o;
    float ac = 0.f;
    for (int k = 0; k < 256; k++) ac += sh[tl][k] * w[k * 10];
    ac += bc[5 * 10 + o];
    int tok = tb + tl;
    if (tok < 3600) clsv[tl][o] = ac;
    __syncthreads();
    if (tid < 32 && tb + tid < 3600) {
        float m = clsv[tid][0];
#pragma unroll
        for (int c = 1; c < 10; c++) m = fmaxf(m, clsv[tid][c]);
        score[tb + tid] = m;  // max-logit == monotone proxy of max-sigmoid
    }
}

// exact top-k(256) ranks, jax.lax.top_k tie semantics
__global__ __launch_bounds__(1024) void k_sel(
    const float* __restrict__ score, int* __restrict__ sel) {
    __shared__ float sc[900];
    int b = blockIdx.x, tid = threadIdx.x;
    for (int i = tid; i < 900; i += 1024) sc[i] = score[b * 900 + i];
    __syncthreads();
    if (tid < 900) {
        float s = sc[tid];
        int r = 0;
        for (int j = 0; j < 900; j++) {
            float sj = sc[j];
            r += ((sj > s) || (sj == s && j < tid)) ? 1 : 0;
        }
        if (r < 256) sel[b * 256 + r] = tid;
    }
}

__global__ __launch_bounds__(256) void k_gather(
    const int* __restrict__ sel, const float* __restrict__ reg3,
    const float* __restrict__ od, float* __restrict__ oe, float* __restrict__ orr) {
    int b = blockIdx.y;
    int r = blockIdx.x * 4 + (threadIdx.x >> 6);
    int lane = threadIdx.x & 63;
    int q = sel[b * 256 + r];
    const float4* src = (const float4*)(od + (size_t)((20 + b) * 900 + q) * 256);
    float4* dst = (float4*)(oe + (size_t)(b * 512 + r) * 256);
    dst[lane] = src[lane];
    if (lane == 0) {
#pragma unroll
        for (int kk = 0; kk < 3; kk++) {
            float v = reg3[(b * 900 + q) * 3 + kk];
            float lo = (kk == 2) ? -5.0f : -51.2f;
            float rng = (kk == 2) ? 8.0f : 102.4f;
            orr[(size_t)(b * 512 + r) * 3 + kk] = fminf(fmaxf((v - lo) / rng, 0.f), 1.f);
        }
    }
}

// ---------------------------------------------------------------------------
extern "C" void kernel_launch(void* const* d_in, const int* in_sizes, int n_in,
                              void* d_out, int out_size, void* d_ws, size_t ws_size,
                              hipStream_t stream) {
    const float* feat   = (const float*)d_in[0];
    const float* l2i    = (const float*)d_in[1];
    const float* prev   = (const float*)d_in[2];
    const float* meme   = (const float*)d_in[3];
    const float* memr   = (const float*)d_in[4];
    const float* memt   = (const float*)d_in[5];
    const float* od     = (const float*)d_in[6];
    const float* rp     = (const float*)d_in[7];
    const float* ip_w   = (const float*)d_in[8];
    const float* ip_b   = (const float*)d_in[9];
    const float* pe_w1  = (const float*)d_in[10];
    const float* pe_b1  = (const float*)d_in[11];
    const float* pe_w2  = (const float*)d_in[12];
    const float* pe_b2  = (const float*)d_in[13];
    const float* ap_w1  = (const float*)d_in[14];
    const float* ap_b1  = (const float*)d_in[15];
    const float* ap_w2  = (const float*)d_in[16];
    const float* ap_b2  = (const float*)d_in[17];
    const float* qe_w1  = (const float*)d_in[18];
    const float* qe_b1  = (const float*)d_in[19];
    const float* qe_w2  = (const float*)d_in[20];
    const float* qe_b2  = (const float*)d_in[21];
    const float* te_w1  = (const float*)d_in[22];
    const float* te_b1  = (const float*)d_in[23];
    const float* te_w2  = (const float*)d_in[24];
    const float* te_b2  = (const float*)d_in[25];
    const float* cls_w1 = (const float*)d_in[26];
    const float* cls_b1 = (const float*)d_in[27];
    const float* cls_g1 = (const float*)d_in[28];
    const float* cls_be1= (const float*)d_in[29];
    const float* cls_w2 = (const float*)d_in[30];
    const float* cls_b2 = (const float*)d_in[31];
    const float* cls_g2 = (const float*)d_in[32];
    const float* cls_be2= (const float*)d_in[33];
    const float* cls_w3 = (const float*)d_in[34];
    const float* cls_b3 = (const float*)d_in[35];
    const float* reg_w1 = (const float*)d_in[36];
    const float* reg_b1 = (const float*)d_in[37];
    const float* reg_w2 = (const float*)d_in[38];
    const float* reg_b2 = (const float*)d_in[39];
    const float* reg_w3 = (const float*)d_in[40];
    const float* reg_b3 = (const float*)d_in[41];

    float* o32    = (float*)d_out;
    float* o_cls  = o32;                 // [0, 216000)
    float* o_reg  = o32 + 216000;        // [216000, 432000)
    float* o_meme = o32 + 432000;        // [432000, 956288)
    float* o_memr = o32 + 956288;
    float* o_memt = o32 + 962432;
    float* o_pos  = o32 + 964480;        // [964480, 5289856)
    float* o_x    = o32 + 5289856;       // [5289856, 9615232)
    float* o_qp   = o32 + 9615232;       // [9615232, 9845632)
    float* o_te   = o32 + 9845632;       // [9845632, 10369920)
    float* o_cm   = o32 + 10369920;

    // ---- d_out-resident scratch (temporally dead at use time) ----
    // decoder phase:
    u16*   h1b  = (u16*)(o32 + 432000);      // 6 slots bf16 [432000, 3196800)
    u16*   h2b  = (u16*)(o32 + 3196800);     // [3196800, 5961600)
    u16*   w1Tc = (u16*)(o32 + 5961600);     // decoder weights bf16, in o_x region
    u16*   w1Tr = (u16*)(o32 + 6158208);
    u16*   w2Tc = (u16*)(o32 + 6354816);
    u16*   w2Tr = (u16*)(o32 + 6551424);     // ends 6748032
    // side-chain (after decoder):
    float* h1f  = o32 + 432000;              // [432000, 1353600)
    float* h2f  = o32 + 1353600;             // [1353600, 2275200)
    // PE phase:
    u16*   c3aT = (u16*)(o32 + 964480);      // [24*704][192] bf16, in o_pos region
    float* sineb = o32 + 432000;             // [432000, 612224) in o_meme region
    float* sinea = o32 + 612224;             // [612224, 792448)
    u16*   hapb  = (u16*)(o32 + 792448);     // [792448, 882560)
    u16*   h1pe  = (u16*)(o32 + 5289856);    // [24][512][704] bf16 == o_x region
    u16*   pe1T  = (u16*)(o32 + 9615232);    // PE weights in o_qp region
    u16*   pe2T  = (u16*)(o32 + 9664384);
    u16*   ap1T  = (u16*)(o32 + 9729920);
    u16*   ap2T  = (u16*)(o32 + 9762688);    // ends 9795456
    // persistents in o_te region (o_te written last):
    float* w_score = o32 + 9845632;          // 3600
    float* w_reg3  = o32 + 9849232;          // 10800 -> 9860032
    float* w_inv   = o32 + 9860032;          // 384   -> 9860416
    int*   w_sel   = (int*)(o32 + 9860416);  // 1024  -> 9861440
    u16*   ipT     = (u16*)(o32 + 9861440);  // 32768 f -> 9894208

    k_inv<<<1, 32, 0, stream>>>(l2i, w_inv);

    // ---- weight prep ----
    k_wtr4<<<dim3(8, 8, 24), 256, 0, stream>>>(cls_w1, reg_w1, cls_w2, reg_w2,
                                               w1Tc, w1Tr, w2Tc, w2Tr, 256, 256, 6);
    k_wtr4<<<dim3(16, 6, 1), 256, 0, stream>>>(pe_w1, pe_w1, pe_w1, pe_w1,
                                               pe1T, pe1T, pe1T, pe1T, 192, 512, 1);
    k_wtr4<<<dim3(8, 16, 1), 256, 0, stream>>>(pe_w2, pe_w2, pe_w2, pe_w2,
                                               pe2T, pe2T, pe2T, pe2T, 512, 256, 1);
    k_wtr4<<<dim3(8, 8, 3), 256, 0, stream>>>(ip_w, ap_w1, ap_w2, ap_w2,
                                              ipT, ap1T, ap2T, ap2T, 256, 256, 1);

    // ---- decoder: cls branch (LN+relu between GEMMs) ----
    k_mfma<1, 0, 0, 0, 0, 0><<<dim3(2, 57, 6), 256, 0, stream>>>(
        od, w1Tc, w1Tc, cls_b1, cls_b1, nullptr, h1b,
        3600, 256, 256, 256, 256, 256, 921600, 65536, 256, 921600, 99, 99, 0);
    k_lnb<<<5400, 256, 0, stream>>>(h1b, cls_g1, cls_be1);
    k_mfma<0, 0, 0, 0, 0, 0><<<dim3(2, 57, 6), 256, 0, stream>>>(
        h1b, w2Tc, w2Tc, cls_b2, cls_b2, nullptr, h2b,
        3600, 256, 256, 256, 256, 256, 921600, 65536, 256, 921600, 99, 99, 1);
    k_lnb<<<5400, 256, 0, stream>>>(h2b, cls_g2, cls_be2);
    k_heads_cls<<<dim3(113, 1, 6), 320, 0, stream>>>(h2b, cls_w3, cls_b3, o_cls, 0);

    // ---- decoder: reg branch (relu in GEMM epilogue) ----
    k_mfma<1, 0, 0, 0, 0, 0><<<dim3(2, 57, 6), 256, 0, stream>>>(
        od, w1Tr, w1Tr, reg_b1, reg_b1, nullptr, h1b,
        3600, 256, 256, 256, 256, 256, 921600, 65536, 256, 921600, 99, 0, 0);
    k_mfma<0, 0, 0, 0, 0, 0><<<dim3(2, 57, 6), 256, 0, stream>>>(
        h1b, w2Tr, w2Tr, reg_b2, reg_b2, nullptr, h2b,
        3600, 256, 256, 256, 256, 256, 921600, 65536, 256, 921600, 99, 0, 1);
    k_heads_reg<<<dim3(113, 1, 6), 320, 0, stream>>>(h2b, reg_w3, reg_b3, o_reg, w_reg3, 0);

    // ---- fp32 side-chain: exact layer-5 cls scores for top-k ordering ----
    k_sgemm<<<dim3(4, 57), 256, 0, stream>>>(od + (size_t)5 * 921600, cls_w1 + 5 * 65536,
                                             cls_b1 + 5 * 256, h1f, 3600);
    k_ln5<<<900, 256, 0, stream>>>(h1f, cls_g1 + 5 * 256, cls_be1 + 5 * 256);
    k_sgemm<<<dim3(4, 57), 256, 0, stream>>>(h1f, cls_w2 + 5 * 65536, cls_b2 + 5 * 256, h2f, 3600);
    k_ln5<<<900, 256, 0, stream>>>(h2f, cls_g2 + 5 * 256, cls_be2 + 5 * 256);
    k_score<<<113, 320, 0, stream>>>(h2f, cls_w3, cls_b3, w_score);

    // ---- PE phase (unchunked) ----
    k_frustum<<<4224, 256, 0, stream>>>(w_inv, c3aT, o_cm);
    k_sinebase<<<704, 256, 0, stream>>>(sineb);
    k_mfma<0, 1, 1, 0, 0, 1><<<dim3(6, 4, 1), 256, 0, stream>>>(
        ap1T, sineb, sineb, ap_b1, ap_b1, nullptr, hapb,
        256, 704, 256, 256, 704, 704, 0, 0, 0, 0, 99, 0, 0);
    k_mfma<0, 1, 0, 1, 0, 1><<<dim3(6, 4, 1), 256, 0, stream>>>(
        ap2T, hapb, hapb, ap_b2, ap_b2, nullptr, sinea,
        256, 704, 256, 256, 704, 704, 0, 0, 0, 0, 99, 99, 0);
    k_mfma<0, 0, 0, 0, 0, 1><<<dim3(6, 8, 24), 256, 0, stream>>>(
        pe1T, c3aT, c3aT, pe_b1, pe_b1, nullptr, h1pe,
        512, 704, 192, 192, 192, 704, 0, 135168, 0, 360448, 99, 0, 0);
    k_mfma<0, 1, 0, 1, 1, 1><<<dim3(6, 4, 24), 256, 0, stream>>>(
        pe2T, h1pe, h1pe, pe_b2, pe_b2, sinea, o_pos,
        256, 704, 512, 512, 704, 704, 0, 360448, 0, 180224, 99, 99, 0);
    k_mfma<0, 1, 1, 1, 0, 1><<<dim3(6, 4, 24), 256, 0, stream>>>(
        ipT, feat, feat, ip_b, ip_b, nullptr, o_x,
        256, 704, 256, 256, 704, 704, 0, 180224, 0, 180224, 99, 99, 0);

    // ---- memory outputs ----
    k_memtail<<<1024, 256, 0, stream>>>(meme, memr, memt, prev, o_meme, o_memr, o_memt);
    k_sel<<<4, 1024, 0, stream>>>(w_score, w_sel);
    k_gather<<<dim3(64, 4), 256, 0, stream>>>(w_sel, w_reg3, od, o_meme, o_memr);

    // ---- small embeddings last (their regions held scratch/persistents) ----
    k_time<<<256, 256, 0, stream>>>(memt, prev, te_w1, te_b1, te_w2, te_b2, o_te);
    k_query<<<225, 256, 0, stream>>>(rp, qe_w1, qe_b1, qe_w2, qe_b2, o_qp);
}